// Round 8
// baseline (774.339 us; speedup 1.0000x reference)
//
#include <hip/hip_runtime.h>
#include <cstdint>
#include <cstddef>

#define NODES  100000
#define EDGES  3200000
#define FIN    128
#define HIDDEN 256
#define EMBD   128
#define GRAPHS 2048

// bucket bin-sort geometry
#define NB   256            // buckets
#define NPB  391            // nodes per bucket (ceil(100000/256))
#define CAP  16384          // staging capacity per bucket
#define TILE 8192           // edges per phase-A block (32KB LDS buf)

typedef _Float16 f16;
typedef f16 f16x2 __attribute__((ext_vector_type(2)));
typedef f16 f16x4 __attribute__((ext_vector_type(4)));
typedef f16 f16x8 __attribute__((ext_vector_type(8)));
typedef float f32x4 __attribute__((ext_vector_type(4)));
typedef unsigned int u32;

// ---------------- Phase A: bin edges by dst-bucket into staging ----------------
// staging word = (src << 9) | (dst - bucket*NPB);  src<2^17, local<391<2^9
__global__ __launch_bounds__(256) void binA_k(const int* __restrict__ src,
                                              const int* __restrict__ dst,
                                              u32* __restrict__ staging,
                                              int* __restrict__ gcur) {
  __shared__ u32 buf[TILE];
  __shared__ int bcnt[NB], bsh[NB], bstart[NB], bcur[NB], gbase[NB];
  const int tid = threadIdx.x;
  const int tb = blockIdx.x * TILE;

  bcnt[tid] = 0;
  __syncthreads();

  // pass 1: count per bucket
#pragma unroll
  for (int j = 0; j < TILE / 256; ++j) {
    int i = tb + j * 256 + tid;
    if (i < EDGES) atomicAdd(&bcnt[dst[i] / NPB], 1);
  }
  __syncthreads();

  // inclusive scan (Hillis-Steele over 256)
  bsh[tid] = bcnt[tid];
  __syncthreads();
  for (int off = 1; off < NB; off <<= 1) {
    int t = (tid >= off) ? bsh[tid - off] : 0;
    __syncthreads();
    bsh[tid] += t;
    __syncthreads();
  }
  bstart[tid] = bsh[tid] - bcnt[tid];
  bcur[tid] = bsh[tid] - bcnt[tid];
  __syncthreads();

  // pass 2: scatter packed words into bucket-ordered LDS
#pragma unroll
  for (int j = 0; j < TILE / 256; ++j) {
    int i = tb + j * 256 + tid;
    if (i < EDGES) {
      int d = dst[i];
      int b = d / NPB;
      u32 w = ((u32)src[i] << 9) | (u32)(d - b * NPB);
      buf[atomicAdd(&bcur[b], 1)] = w;
    }
  }
  // reserve global ranges (256 atomics per tile)
  gbase[tid] = atomicAdd(&gcur[tid], bcnt[tid]);
  __syncthreads();

  // copy-out: thread t owns bucket t; consecutive stores -> dense lines
  {
    int c = bcnt[tid], st = bstart[tid];
    u32* outp = staging + (size_t)tid * CAP + gbase[tid];
    for (int k = 0; k < c; ++k) outp[k] = buf[st + k];
  }
}

// ---------------- bucket-base exclusive scan (1 block) ----------------
__global__ void bscan_k(const int* __restrict__ gcur, int* __restrict__ bbase) {
  __shared__ int sh[NB];
  int tid = threadIdx.x;
  int v = gcur[tid];
  sh[tid] = v;
  __syncthreads();
  for (int off = 1; off < NB; off <<= 1) {
    int t = (tid >= off) ? sh[tid - off] : 0;
    __syncthreads();
    sh[tid] += t;
    __syncthreads();
  }
  bbase[tid] = sh[tid] - v;  // exclusive
}

// ---------------- Phase B: per-bucket CSR finalize + fused x-prescale ----------------
__global__ __launch_bounds__(512) void binB_k(const u32* __restrict__ staging,
                                              const int* __restrict__ gcur,
                                              const int* __restrict__ bbase,
                                              int* __restrict__ row_ptr,
                                              float* __restrict__ dinv,
                                              int* __restrict__ csr_src,
                                              const float* __restrict__ x,
                                              f16* __restrict__ xs) {
  __shared__ int ncnt[512];
  __shared__ int ncur[512];
  __shared__ float sdinv[512];
  const int b = blockIdx.x;
  const int tid = threadIdx.x;
  const int m = gcur[b];
  const int base = bbase[b];
  const int nb0 = b * NPB;
  const int nn = min(NPB, NODES - nb0);
  const u32* sb = staging + (size_t)b * CAP;

  ncnt[tid] = 0;
  __syncthreads();

  // count per local node
  for (int k = tid; k < m; k += 512) atomicAdd(&ncnt[sb[k] & 511], 1);
  __syncthreads();

  int v = ncnt[tid];
  // in-place inclusive scan over 512
  for (int off = 1; off < 512; off <<= 1) {
    int t = (tid >= off) ? ncnt[tid - off] : 0;
    __syncthreads();
    ncnt[tid] += t;
    __syncthreads();
  }
  int incl = ncnt[tid];
  float dv = rsqrtf((float)(v + 1));
  if (tid < nn) {
    row_ptr[nb0 + tid + 1] = base + incl;
    dinv[nb0 + tid] = dv;
    sdinv[tid] = dv;
    ncur[tid] = base + incl - v;  // global cursor start (exclusive)
  }
  if (b == 0 && tid == 0) row_ptr[0] = 0;
  __syncthreads();

  // scatter src into block-owned contiguous csr region (dense writes)
  for (int k = tid; k < m; k += 512) {
    u32 w = sb[k];
    int pos = atomicAdd(&ncur[w & 511], 1);
    csr_src[pos] = (int)(w >> 9);
  }

  // fused prescale for this block's nodes: xs = f16(dinv * x), 128-wide
  for (int idx = tid; idx < nn * 32; idx += 512) {
    int row = idx >> 5;            // local row
    int c4 = idx & 31;             // float4 index within row
    float d = sdinv[row];
    float4 vx = *(const float4*)(x + (size_t)(nb0 + row) * FIN + c4 * 4);
    f16x4 o = {(f16)(d * vx.x), (f16)(d * vx.y), (f16)(d * vx.z), (f16)(d * vx.w)};
    *(f16x4*)(xs + (size_t)(nb0 + row) * FIN + c4 * 4) = o;
  }
}

// ---------------- fused weight convert+transpose for W1,W2,W3 ----------------
__global__ void convw3_k(const float* __restrict__ W1, const float* __restrict__ W2,
                         const float* __restrict__ W3, f16* __restrict__ Wt1,
                         f16* __restrict__ Wt2, f16* __restrict__ Wt3) {
  int i = blockIdx.x * blockDim.x + threadIdx.x;
  // W1: 128x256 (32768), W2: 256x256 (65536), W3: 256x128 (32768)
  if (i < 32768) {
    int k = i >> 8, m = i & 255;
    Wt1[(size_t)m * FIN + k] = (f16)W1[i];
  } else if (i < 98304) {
    int j = i - 32768;
    int k = j >> 8, m = j & 255;
    Wt2[(size_t)m * HIDDEN + k] = (f16)W2[j];
  } else if (i < 131072) {
    int j = i - 98304;
    int k = j >> 7, m = j & 127;
    Wt3[(size_t)m * HIDDEN + k] = (f16)W3[j];
  }
}

// ---------------- fused L1: agg(128-wide) -> LDS -> MFMA GEMM (K=128, M=256) ----------------
// Block = 128 nodes, 512 threads (8 waves). Gather phase: wave owns 16 nodes,
// 2 at a time (half-wave x 32 lanes x f16x4). GEMM: wave rows = its 16 nodes,
// B read directly from Wt1 (64KB, L2-broadcast). Output H1s = dinv*relu(.)+b to C (F1).
__global__ __launch_bounds__(512, 4) void fused_l1(const f16* __restrict__ A,
                                                   const f16* __restrict__ Wt1,
                                                   const float* __restrict__ b1,
                                                   const int* __restrict__ row_ptr,
                                                   const int* __restrict__ csr_src,
                                                   const float* __restrict__ dinv,
                                                   f16* __restrict__ C) {
  __shared__ f16 As[128][136];  // stride 136: 2-way max bank aliasing on frag reads
  const int tid = threadIdx.x;
  const int rowbase = blockIdx.x * 128;
  const int w = tid >> 6;        // wave 0..7
  const int l = tid & 63;
  const int half = (tid >> 5) & 1;
  const int lane = tid & 31;
  const int c0 = lane * 4;

  // ---- gather phase ----
  const f16* __restrict__ inc = A + c0;
  for (int p = 0; p < 8; ++p) {
    const int lr = w * 16 + p * 2 + half;
    const int node = rowbase + lr;
    if (node < NODES) {
      float acc[4] = {0.f, 0.f, 0.f, 0.f};
      const int beg = row_ptr[node], end = row_ptr[node + 1];
      int k = beg;
      for (; k + 8 <= end; k += 8) {
        int s[8];
#pragma unroll
        for (int u = 0; u < 8; ++u) s[u] = csr_src[k + u];
        f16x4 hv[8];
#pragma unroll
        for (int u = 0; u < 8; ++u) hv[u] = *(const f16x4*)(inc + (size_t)s[u] * FIN);
#pragma unroll
        for (int u = 0; u < 8; ++u)
#pragma unroll
          for (int v = 0; v < 4; ++v) acc[v] += (float)hv[u][v];
      }
      for (; k < end; ++k) {
        f16x4 hv = *(const f16x4*)(inc + (size_t)csr_src[k] * FIN);
#pragma unroll
        for (int v = 0; v < 4; ++v) acc[v] += (float)hv[v];
      }
      {  // self loop
        f16x4 hv = *(const f16x4*)(inc + (size_t)node * FIN);
#pragma unroll
        for (int v = 0; v < 4; ++v) acc[v] += (float)hv[v];
      }
      float di = dinv[node];
      f16x4 o = {(f16)(di * acc[0]), (f16)(di * acc[1]),
                 (f16)(di * acc[2]), (f16)(di * acc[3])};
      *(f16x4*)&As[lr][c0] = o;
    }
  }
  __syncthreads();

  // ---- GEMM phase: C[128 rows][256 cols] in 2 col-halves ----
  const int fr = l & 15;   // frag row (A) / frag col (B,C)
  const int kq = l >> 4;   // 0..3
#pragma unroll
  for (int ch = 0; ch < 2; ++ch) {
    f32x4 acc[8];
#pragma unroll
    for (int cf = 0; cf < 8; ++cf) acc[cf] = (f32x4){0.f, 0.f, 0.f, 0.f};
#pragma unroll
    for (int kk = 0; kk < 4; ++kk) {
      f16x8 a = *(const f16x8*)&As[w * 16 + fr][kk * 32 + kq * 8];
#pragma unroll
      for (int cf = 0; cf < 8; ++cf) {
        int col = ch * 128 + cf * 16 + fr;
        f16x8 b = *(const f16x8*)(Wt1 + (size_t)col * FIN + kk * 32 + kq * 8);
        acc[cf] = __builtin_amdgcn_mfma_f32_16x16x32_f16(a, b, acc[cf], 0, 0, 0);
      }
    }
#pragma unroll
    for (int cf = 0; cf < 8; ++cf) {
      int col = ch * 128 + cf * 16 + fr;
      float bv = b1[col];
#pragma unroll
      for (int r = 0; r < 4; ++r) {
        int row = rowbase + w * 16 + kq * 4 + r;
        if (row < NODES) {
          float v = fmaxf(acc[cf][r] + bv, 0.f) * dinv[row];
          C[(size_t)row * HIDDEN + col] = (f16)v;
        }
      }
    }
  }
}

// ---------------- aggregation (f16 in, fp32 accum), 2 nodes/wave ----------------
// in is dinv-prescaled: out[i] = dinv[i]*(sum_{s in N(i)} in[s] + in[i]); FINAL adds bias, f16 out
template <int V, bool FINAL>
__global__ __launch_bounds__(256) void agg_h(const f16* __restrict__ in, f16* __restrict__ out,
                      const int* __restrict__ row_ptr, const int* __restrict__ csr_src,
                      const float* __restrict__ dinv, const float* __restrict__ bias) {
  constexpr int D = V * 32;   // row width in f16
  constexpr int U = 8;        // gathers in flight per node stream (16/wave)
  const int wid = (blockIdx.x * blockDim.x + threadIdx.x) >> 6;
  const int half = (threadIdx.x >> 5) & 1;
  const int lane = threadIdx.x & 31;
  const int node = wid * 2 + half;
  if (node >= NODES) return;
  const int c0 = lane * V;
  const f16* __restrict__ inc = in + c0;

  float acc[V];
#pragma unroll
  for (int v = 0; v < V; ++v) acc[v] = 0.f;

  const int beg = row_ptr[node], end = row_ptr[node + 1];
  int k = beg;
  if constexpr (V == 8) {
    for (; k + U <= end; k += U) {
      int s[U];
#pragma unroll
      for (int u = 0; u < U; ++u) s[u] = csr_src[k + u];
      f16x8 hv[U];
#pragma unroll
      for (int u = 0; u < U; ++u) hv[u] = *(const f16x8*)(inc + (size_t)s[u] * D);
#pragma unroll
      for (int u = 0; u < U; ++u)
#pragma unroll
        for (int v = 0; v < V; ++v) acc[v] += (float)hv[u][v];
    }
    for (; k < end; ++k) {
      f16x8 hv = *(const f16x8*)(inc + (size_t)csr_src[k] * D);
#pragma unroll
      for (int v = 0; v < V; ++v) acc[v] += (float)hv[v];
    }
    f16x8 hv = *(const f16x8*)(inc + (size_t)node * D);  // self loop
#pragma unroll
    for (int v = 0; v < V; ++v) acc[v] += (float)hv[v];
  } else {
    for (; k + U <= end; k += U) {
      int s[U];
#pragma unroll
      for (int u = 0; u < U; ++u) s[u] = csr_src[k + u];
      f16x4 hv[U];
#pragma unroll
      for (int u = 0; u < U; ++u) hv[u] = *(const f16x4*)(inc + (size_t)s[u] * D);
#pragma unroll
      for (int u = 0; u < U; ++u)
#pragma unroll
        for (int v = 0; v < V; ++v) acc[v] += (float)hv[u][v];
    }
    for (; k < end; ++k) {
      f16x4 hv = *(const f16x4*)(inc + (size_t)csr_src[k] * D);
#pragma unroll
      for (int v = 0; v < V; ++v) acc[v] += (float)hv[v];
    }
    f16x4 hv = *(const f16x4*)(inc + (size_t)node * D);  // self loop
#pragma unroll
    for (int v = 0; v < V; ++v) acc[v] += (float)hv[v];
  }

  const float di = dinv[node];
  if constexpr (FINAL) {  // V==4: h3 = di*acc + bias, f16 out
    f16x4 o;
#pragma unroll
    for (int v = 0; v < V; ++v) o[v] = (f16)(di * acc[v] + bias[c0 + v]);
    *(f16x4*)(out + (size_t)node * D + c0) = o;
  } else {
    if constexpr (V == 8) {
      f16x8 o;
#pragma unroll
      for (int v = 0; v < V; ++v) o[v] = (f16)(di * acc[v]);
      *(f16x8*)(out + (size_t)node * D + c0) = o;
    } else {
      f16x4 o;
#pragma unroll
      for (int v = 0; v < V; ++v) o[v] = (f16)(di * acc[v]);
      *(f16x4*)(out + (size_t)node * D + c0) = o;
    }
  }
}

// ---------------- wide f16 MFMA GEMM: C[N,256] = dinv*relu(A[N,K]@W[K,256]+b) ----------------
template <int K>
__global__ __launch_bounds__(256, 2) void gemm_w(const f16* __restrict__ A,
                                                 const f16* __restrict__ Wt,
                                                 const float* __restrict__ bias,
                                                 const float* __restrict__ dinv,
                                                 f16* __restrict__ C, int N) {
  constexpr int M = 256;
  __shared__ f16 As[128][40];
  __shared__ f16 Bs[256][40];

  const int tid = threadIdx.x;
  const int rowbase = blockIdx.x * 128;
  const int l = tid & 63;
  const int wv = tid >> 6;
  const int wr = (wv >> 1) * 64;   // 0 / 64
  const int wc = (wv & 1) * 128;   // 0 / 128
  const int lr = tid >> 1;
  const int lc = (tid & 1) * 16;

  f32x4 acc[4][8];
#pragma unroll
  for (int i = 0; i < 4; ++i)
#pragma unroll
    for (int j = 0; j < 8; ++j) acc[i][j] = (f32x4){0.f, 0.f, 0.f, 0.f};

  const int arow = min(rowbase + lr, N - 1);
  const f16* aptr = A + (size_t)arow * K + lc;
  const f16* bptr = Wt + (size_t)tid * K;

  for (int kb = 0; kb < K; kb += 32) {
    *(f16x8*)&As[lr][lc]     = *(const f16x8*)(aptr + kb);
    *(f16x8*)&As[lr][lc + 8] = *(const f16x8*)(aptr + kb + 8);
#pragma unroll
    for (int q = 0; q < 4; ++q)
      *(f16x8*)&Bs[tid][q * 8] = *(const f16x8*)(bptr + kb + q * 8);
    __syncthreads();

    f16x8 a[4], b[8];
#pragma unroll
    for (int f = 0; f < 4; ++f)
      a[f] = *(const f16x8*)&As[wr + f * 16 + (l & 15)][(l >> 4) * 8];
#pragma unroll
    for (int g = 0; g < 8; ++g)
      b[g] = *(const f16x8*)&Bs[wc + g * 16 + (l & 15)][(l >> 4) * 8];
#pragma unroll
    for (int fm = 0; fm < 4; ++fm)
#pragma unroll
      for (int g = 0; g < 8; ++g)
        acc[fm][g] = __builtin_amdgcn_mfma_f32_16x16x32_f16(a[fm], b[g], acc[fm][g], 0, 0, 0);
    __syncthreads();
  }

  float bv[8];
#pragma unroll
  for (int g = 0; g < 8; ++g) bv[g] = bias[wc + g * 16 + (l & 15)];

#pragma unroll
  for (int fm = 0; fm < 4; ++fm) {
#pragma unroll
    for (int r = 0; r < 4; ++r) {
      int row = rowbase + wr + fm * 16 + (l >> 4) * 4 + r;
      if (row >= N) continue;
      float dv = dinv[row];
#pragma unroll
      for (int g = 0; g < 8; ++g) {
        int col = wc + g * 16 + (l & 15);
        float v = fmaxf(acc[fm][g][r] + bv[g], 0.f);
        C[(size_t)row * M + col] = (f16)(v * dv);
      }
    }
  }
}

// ---------------- square f16 MFMA GEMM (for the 256->128 layer) ----------------
template <int K, bool RELU, bool BIAS, bool DSCALE>
__global__ __launch_bounds__(256) void gemm_h(const f16* __restrict__ A,
                                              const f16* __restrict__ Wt,
                                              const float* __restrict__ bias,
                                              const float* __restrict__ dinv,
                                              f16* __restrict__ C, int N, int M) {
  __shared__ f16 As[128][40];
  __shared__ f16 Bs[128][40];

  const int tid = threadIdx.x;
  const int rowbase = blockIdx.x * 128;
  const int colbase = blockIdx.y * 128;
  const int l = tid & 63;
  const int wr = ((tid >> 6) >> 1) * 64;
  const int wc = ((tid >> 6) & 1) * 64;
  const int lr = tid >> 1;
  const int lc = (tid & 1) * 16;

  f32x4 acc[4][4];
#pragma unroll
  for (int i = 0; i < 4; ++i)
#pragma unroll
    for (int j = 0; j < 4; ++j) acc[i][j] = (f32x4){0.f, 0.f, 0.f, 0.f};

  const int arow = min(rowbase + lr, N - 1);
  const f16* aptr = A + (size_t)arow * K + lc;
  const f16* bptr = Wt + (size_t)(colbase + lr) * K + lc;

  for (int kb = 0; kb < K; kb += 32) {
    *(f16x8*)&As[lr][lc]     = *(const f16x8*)(aptr + kb);
    *(f16x8*)&As[lr][lc + 8] = *(const f16x8*)(aptr + kb + 8);
    *(f16x8*)&Bs[lr][lc]     = *(const f16x8*)(bptr + kb);
    *(f16x8*)&Bs[lr][lc + 8] = *(const f16x8*)(bptr + kb + 8);
    __syncthreads();

    f16x8 a[4], b[4];
#pragma unroll
    for (int f = 0; f < 4; ++f) {
      a[f] = *(const f16x8*)&As[wr + f * 16 + (l & 15)][(l >> 4) * 8];
      b[f] = *(const f16x8*)&Bs[wc + f * 16 + (l & 15)][(l >> 4) * 8];
    }
#pragma unroll
    for (int fm = 0; fm < 4; ++fm)
#pragma unroll
      for (int fn = 0; fn < 4; ++fn)
        acc[fm][fn] = __builtin_amdgcn_mfma_f32_16x16x32_f16(a[fm], b[fn], acc[fm][fn], 0, 0, 0);
    __syncthreads();
  }

  float bv[4];
#pragma unroll
  for (int fn = 0; fn < 4; ++fn)
    bv[fn] = BIAS ? bias[colbase + wc + fn * 16 + (l & 15)] : 0.f;

#pragma unroll
  for (int fm = 0; fm < 4; ++fm) {
#pragma unroll
    for (int r = 0; r < 4; ++r) {
      int row = rowbase + wr + fm * 16 + (l >> 4) * 4 + r;
      if (row >= N) continue;
      float dv = DSCALE ? dinv[row] : 1.f;
#pragma unroll
      for (int fn = 0; fn < 4; ++fn) {
        int col = colbase + wc + fn * 16 + (l & 15);
        float v = acc[fm][fn][r] + bv[fn];
        if (RELU) v = fmaxf(v, 0.f);
        C[(size_t)row * M + col] = (f16)(v * dv);
      }
    }
  }
}

// ---------------- fp32 GEMM for the tiny head (N=2048) ----------------
template <int K, bool RELU, bool HAS_BIAS>
__global__ __launch_bounds__(256) void gemm_k(const float* __restrict__ A,
                                              const float* __restrict__ W,
                                              const float* __restrict__ bias,
                                              float* __restrict__ C, int N, int M) {
  constexpr int KB = 16;
  __shared__ float As[KB][128];
  __shared__ float Ws[KB][128];

  const int tid = threadIdx.x;
  const int rowbase = blockIdx.x * 128;
  const int colbase = blockIdx.y * 128;
  const int tr = tid >> 4;
  const int tc = tid & 15;
  const int ar = tid >> 1;
  const int ac4_0 = (tid & 1) * 2;
  const int wk = tid >> 4;
  const int wc4_0 = (tid & 15) * 2;

  float acc[8][8];
#pragma unroll
  for (int i = 0; i < 8; ++i)
#pragma unroll
    for (int j = 0; j < 8; ++j) acc[i][j] = 0.f;

  for (int kb = 0; kb < K; kb += KB) {
#pragma unroll
    for (int q = 0; q < 2; ++q) {
      int c4 = ac4_0 + q;
      int grow = rowbase + ar;
      float4 v = make_float4(0.f, 0.f, 0.f, 0.f);
      if (grow < N) v = *(const float4*)(A + (size_t)grow * K + kb + c4 * 4);
      As[c4 * 4 + 0][ar] = v.x;
      As[c4 * 4 + 1][ar] = v.y;
      As[c4 * 4 + 2][ar] = v.z;
      As[c4 * 4 + 3][ar] = v.w;
    }
#pragma unroll
    for (int q = 0; q < 2; ++q) {
      int c4 = wc4_0 + q;
      float4 v = *(const float4*)(W + (size_t)(kb + wk) * M + colbase + c4 * 4);
      *(float4*)&Ws[wk][c4 * 4] = v;
    }
    __syncthreads();

#pragma unroll
    for (int kk = 0; kk < KB; ++kk) {
      float4 a0 = *(const float4*)&As[kk][tr * 4];
      float4 a1 = *(const float4*)&As[kk][tr * 4 + 64];
      float4 w0 = *(const float4*)&Ws[kk][tc * 4];
      float4 w1 = *(const float4*)&Ws[kk][tc * 4 + 64];
      float a[8] = {a0.x, a0.y, a0.z, a0.w, a1.x, a1.y, a1.z, a1.w};
      float w[8] = {w0.x, w0.y, w0.z, w0.w, w1.x, w1.y, w1.z, w1.w};
#pragma unroll
      for (int i = 0; i < 8; ++i)
#pragma unroll
        for (int j = 0; j < 8; ++j) acc[i][j] = fmaf(a[i], w[j], acc[i][j]);
    }
    __syncthreads();
  }

#pragma unroll
  for (int i = 0; i < 8; ++i) {
    int r = rowbase + ((i < 4) ? (tr * 4 + i) : (64 + tr * 4 + (i - 4)));
    if (r >= N) continue;
#pragma unroll
    for (int jh = 0; jh < 2; ++jh) {
      int c = colbase + tc * 4 + jh * 64;
      float4 o;
      o.x = acc[i][jh * 4 + 0];
      o.y = acc[i][jh * 4 + 1];
      o.z = acc[i][jh * 4 + 2];
      o.w = acc[i][jh * 4 + 3];
      if (HAS_BIAS) {
        o.x += bias[c]; o.y += bias[c + 1]; o.z += bias[c + 2]; o.w += bias[c + 3];
      }
      if (RELU) {
        o.x = fmaxf(o.x, 0.f); o.y = fmaxf(o.y, 0.f);
        o.z = fmaxf(o.z, 0.f); o.w = fmaxf(o.w, 0.f);
      }
      *(float4*)(C + (size_t)r * M + c) = o;
    }
  }
}

// ---------------- mean pooling per graph (batch sorted), f16 input ----------------
__global__ void pool_k(const f16* __restrict__ h, const int* __restrict__ batch,
                       float* __restrict__ pooled) {
  int g = blockIdx.x;
  int j = threadIdx.x;  // 128 threads = EMBD
  int lo = 0, hi = NODES;
  while (lo < hi) { int mid = (lo + hi) >> 1; if (batch[mid] < g) lo = mid + 1; else hi = mid; }
  int start = lo;
  int lo2 = start, hi2 = NODES;
  while (lo2 < hi2) { int mid = (lo2 + hi2) >> 1; if (batch[mid] < g + 1) lo2 = mid + 1; else hi2 = mid; }
  int end = lo2;
  float s = 0.f;
  for (int r = start; r < end; ++r) s += (float)h[(size_t)r * EMBD + j];
  float c = (float)(end - start);
  pooled[g * EMBD + j] = s / fmaxf(c, 1.f);
}

// ---------------- head: logits = z2 @ Wc3[128,2] + bc3 ----------------
__global__ void head_k(const float* __restrict__ z2, const float* __restrict__ Wc3,
                       const float* __restrict__ bc3, float* __restrict__ out) {
  int wv = (blockIdx.x * blockDim.x + threadIdx.x) >> 6;
  int lane = threadIdx.x & 63;
  if (wv >= GRAPHS) return;
  float2 z = *(const float2*)(z2 + (size_t)wv * 128 + lane * 2);
  int j0 = lane * 2;
  float a0 = z.x * Wc3[j0 * 2 + 0] + z.y * Wc3[(j0 + 1) * 2 + 0];
  float a1 = z.x * Wc3[j0 * 2 + 1] + z.y * Wc3[(j0 + 1) * 2 + 1];
  for (int off = 32; off; off >>= 1) {
    a0 += __shfl_down(a0, off);
    a1 += __shfl_down(a1, off);
  }
  if (lane == 0) {
    out[wv * 2 + 0] = a0 + bc3[0];
    out[wv * 2 + 1] = a1 + bc3[1];
  }
}

extern "C" void kernel_launch(void* const* d_in, const int* in_sizes, int n_in,
                              void* d_out, int out_size, void* d_ws, size_t ws_size,
                              hipStream_t stream) {
  const float* x    = (const float*)d_in[0];
  const int*   ei   = (const int*)d_in[1];
  const int*   batch= (const int*)d_in[2];
  const float* W1 = (const float*)d_in[3];  const float* b1 = (const float*)d_in[4];
  const float* W2 = (const float*)d_in[5];  const float* b2 = (const float*)d_in[6];
  const float* W3 = (const float*)d_in[7];  const float* b3 = (const float*)d_in[8];
  const float* Wc1= (const float*)d_in[9];  const float* bc1= (const float*)d_in[10];
  const float* Wc2= (const float*)d_in[11]; const float* bc2= (const float*)d_in[12];
  const float* Wc3= (const float*)d_in[13]; const float* bc3= (const float*)d_in[14];
  float* out = (float*)d_out;

  char* ws = (char*)d_ws;
  size_t off = 0;
  auto alloc = [&](size_t bytes) -> void* {
    void* p = ws + off;
    off = (off + bytes + 255) & ~(size_t)255;
    return p;
  };
  f16*   F0      = (f16*)alloc((size_t)NODES * 256 * 2);
  f16*   F1      = (f16*)alloc((size_t)NODES * 256 * 2);
  f16*   hbuf    = (f16*)alloc((size_t)NODES * 128 * 2);
  int*   csr_src = (int*)alloc((size_t)EDGES * 4);
  u32*   staging = (u32*)alloc((size_t)NB * CAP * 4);
  int*   row_ptr = (int*)alloc((size_t)(NODES + 1) * 4);
  float* dinv    = (float*)alloc((size_t)NODES * 4);
  int*   gcur    = (int*)alloc(NB * 4);
  int*   bbase   = (int*)alloc(NB * 4);
  f16*   Wt1     = (f16*)alloc((size_t)FIN * HIDDEN * 2);
  f16*   Wt2     = (f16*)alloc((size_t)HIDDEN * HIDDEN * 2);
  f16*   Wt3     = (f16*)alloc((size_t)HIDDEN * EMBD * 2);
  // fp32 overlays in F1 (free after the L3 pre-GEMM consumed it)
  float* pooled = (float*)F1;
  float* z1     = pooled + (size_t)GRAPHS * EMBD;
  float* z2     = z1 + (size_t)GRAPHS * HIDDEN;

  const int* srcA = ei;
  const int* dstA = ei + EDGES;

  // ---- CSR build: two-phase LDS bin-sort (+fused prescale -> F0 128-wide) ----
  hipMemsetAsync(gcur, 0, NB * 4, stream);
  binA_k<<<(EDGES + TILE - 1) / TILE, 256, 0, stream>>>(srcA, dstA, staging, gcur);
  bscan_k<<<1, NB, 0, stream>>>(gcur, bbase);
  binB_k<<<NB, 512, 0, stream>>>(staging, gcur, bbase, row_ptr, dinv, csr_src, x, F0);

  convw3_k<<<(131072 + 255) / 256, 256, 0, stream>>>(W1, W2, W3, Wt1, Wt2, Wt3);

  const int aggBlocks = ((NODES + 1) / 2 * 64 + 255) / 256;  // 12500
  const int gemmRows = (NODES + 127) / 128;                  // 782

  // L1 fused: gather AX (128) into LDS, MFMA @W1 -> H1s [256 f16] in F1
  fused_l1<<<gemmRows, 512, 0, stream>>>(F0, Wt1, b1, row_ptr, csr_src, dinv, F1);
  // L2: AH1 = dinv*(sum H1s) [256 f16] F1->F0; H2s = dinv*relu(AH1@W2+b2) F0->F1
  agg_h<8, false><<<aggBlocks, 256, 0, stream>>>(F1, F0, row_ptr, csr_src, dinv, nullptr);
  gemm_w<HIDDEN><<<gemmRows, 256, 0, stream>>>(F0, Wt2, b2, dinv, F1, NODES);
  // L3: G3s = H2s@W3 [128 f16] F1->F0; h3 = dinv*(sum G3s)+b3 [128 f16] F0->hbuf
  gemm_h<HIDDEN, false, false, false><<<dim3(gemmRows, 1), 256, 0, stream>>>(F1, Wt3, nullptr, nullptr, F0, NODES, EMBD);
  agg_h<4, true><<<aggBlocks, 256, 0, stream>>>(F0, hbuf, row_ptr, csr_src, dinv, b3);

  // pooling + MLP head (fp32)
  pool_k<<<GRAPHS, 128, 0, stream>>>(hbuf, batch, pooled);
  gemm_k<EMBD, true, true><<<dim3((GRAPHS + 127) / 128, 2), 256, 0, stream>>>(pooled, Wc1, bc1, z1, GRAPHS, HIDDEN);
  gemm_k<HIDDEN, true, true><<<dim3((GRAPHS + 127) / 128, 1), 256, 0, stream>>>(z1, Wc2, bc2, z2, GRAPHS, EMBD);
  head_k<<<GRAPHS / 4, 256, 0, stream>>>(z2, Wc3, bc3, out);
}

// Round 9
// 694.504 us; speedup vs baseline: 1.1150x; 1.1150x over previous
//
#include <hip/hip_runtime.h>
#include <cstdint>
#include <cstddef>

#define NODES  100000
#define EDGES  3200000
#define FIN    128
#define HIDDEN 256
#define EMBD   128
#define GRAPHS 2048

// bucket bin-sort geometry
#define NB   256            // buckets
#define NPB  391            // nodes per bucket (ceil(100000/256))
#define CAP  16384          // staging capacity per bucket
#define TILE 8192           // edges per phase-A block (32KB LDS buf)

typedef _Float16 f16;
typedef f16 f16x2 __attribute__((ext_vector_type(2)));
typedef f16 f16x4 __attribute__((ext_vector_type(4)));
typedef f16 f16x8 __attribute__((ext_vector_type(8)));
typedef float f32x4 __attribute__((ext_vector_type(4)));
typedef unsigned int u32;

// ---------------- Phase A: bin edges by dst-bucket into staging ----------------
// staging word = (src << 9) | (dst - bucket*NPB);  src<2^17, local<391<2^9
__global__ __launch_bounds__(256) void binA_k(const int* __restrict__ src,
                                              const int* __restrict__ dst,
                                              u32* __restrict__ staging,
                                              int* __restrict__ gcur) {
  __shared__ u32 buf[TILE];
  __shared__ int bcnt[NB], bsh[NB], bstart[NB], bcur[NB], gbase[NB];
  const int tid = threadIdx.x;
  const int tb = blockIdx.x * TILE;

  bcnt[tid] = 0;
  __syncthreads();

  // pass 1: count per bucket
#pragma unroll
  for (int j = 0; j < TILE / 256; ++j) {
    int i = tb + j * 256 + tid;
    if (i < EDGES) atomicAdd(&bcnt[dst[i] / NPB], 1);
  }
  __syncthreads();

  // inclusive scan (Hillis-Steele over 256)
  bsh[tid] = bcnt[tid];
  __syncthreads();
  for (int off = 1; off < NB; off <<= 1) {
    int t = (tid >= off) ? bsh[tid - off] : 0;
    __syncthreads();
    bsh[tid] += t;
    __syncthreads();
  }
  bstart[tid] = bsh[tid] - bcnt[tid];
  bcur[tid] = bsh[tid] - bcnt[tid];
  __syncthreads();

  // pass 2: scatter packed words into bucket-ordered LDS
#pragma unroll
  for (int j = 0; j < TILE / 256; ++j) {
    int i = tb + j * 256 + tid;
    if (i < EDGES) {
      int d = dst[i];
      int b = d / NPB;
      u32 w = ((u32)src[i] << 9) | (u32)(d - b * NPB);
      buf[atomicAdd(&bcur[b], 1)] = w;
    }
  }
  // reserve global ranges (256 atomics per tile)
  gbase[tid] = atomicAdd(&gcur[tid], bcnt[tid]);
  __syncthreads();

  // copy-out: thread t owns bucket t; consecutive stores -> dense lines
  {
    int c = bcnt[tid], st = bstart[tid];
    u32* outp = staging + (size_t)tid * CAP + gbase[tid];
    for (int k = 0; k < c; ++k) outp[k] = buf[st + k];
  }
}

// ---------------- bucket-base exclusive scan (1 block) ----------------
__global__ void bscan_k(const int* __restrict__ gcur, int* __restrict__ bbase) {
  __shared__ int sh[NB];
  int tid = threadIdx.x;
  int v = gcur[tid];
  sh[tid] = v;
  __syncthreads();
  for (int off = 1; off < NB; off <<= 1) {
    int t = (tid >= off) ? sh[tid - off] : 0;
    __syncthreads();
    sh[tid] += t;
    __syncthreads();
  }
  bbase[tid] = sh[tid] - v;  // exclusive
}

// ---------------- Phase B: per-bucket CSR finalize + fused x-prescale ----------------
__global__ __launch_bounds__(512) void binB_k(const u32* __restrict__ staging,
                                              const int* __restrict__ gcur,
                                              const int* __restrict__ bbase,
                                              int* __restrict__ row_ptr,
                                              float* __restrict__ dinv,
                                              int* __restrict__ csr_src,
                                              const float* __restrict__ x,
                                              f16* __restrict__ xs) {
  __shared__ int ncnt[512];
  __shared__ int ncur[512];
  __shared__ float sdinv[512];
  const int b = blockIdx.x;
  const int tid = threadIdx.x;
  const int m = gcur[b];
  const int base = bbase[b];
  const int nb0 = b * NPB;
  const int nn = min(NPB, NODES - nb0);
  const u32* sb = staging + (size_t)b * CAP;

  ncnt[tid] = 0;
  __syncthreads();

  // count per local node
  for (int k = tid; k < m; k += 512) atomicAdd(&ncnt[sb[k] & 511], 1);
  __syncthreads();

  int v = ncnt[tid];
  // in-place inclusive scan over 512
  for (int off = 1; off < 512; off <<= 1) {
    int t = (tid >= off) ? ncnt[tid - off] : 0;
    __syncthreads();
    ncnt[tid] += t;
    __syncthreads();
  }
  int incl = ncnt[tid];
  float dv = rsqrtf((float)(v + 1));
  if (tid < nn) {
    row_ptr[nb0 + tid + 1] = base + incl;
    dinv[nb0 + tid] = dv;
    sdinv[tid] = dv;
    ncur[tid] = base + incl - v;  // global cursor start (exclusive)
  }
  if (b == 0 && tid == 0) row_ptr[0] = 0;
  __syncthreads();

  // scatter src into block-owned contiguous csr region (dense writes)
  for (int k = tid; k < m; k += 512) {
    u32 w = sb[k];
    int pos = atomicAdd(&ncur[w & 511], 1);
    csr_src[pos] = (int)(w >> 9);
  }

  // fused prescale for this block's nodes: xs = f16(dinv * x), 128-wide
  for (int idx = tid; idx < nn * 32; idx += 512) {
    int row = idx >> 5;            // local row
    int c4 = idx & 31;             // float4 index within row
    float d = sdinv[row];
    float4 vx = *(const float4*)(x + (size_t)(nb0 + row) * FIN + c4 * 4);
    f16x4 o = {(f16)(d * vx.x), (f16)(d * vx.y), (f16)(d * vx.z), (f16)(d * vx.w)};
    *(f16x4*)(xs + (size_t)(nb0 + row) * FIN + c4 * 4) = o;
  }
}

// ---------------- fused weight convert+transpose for W1,W2,W3 ----------------
__global__ void convw3_k(const float* __restrict__ W1, const float* __restrict__ W2,
                         const float* __restrict__ W3, f16* __restrict__ Wt1,
                         f16* __restrict__ Wt2, f16* __restrict__ Wt3) {
  int i = blockIdx.x * blockDim.x + threadIdx.x;
  // W1: 128x256 (32768), W2: 256x256 (65536), W3: 256x128 (32768)
  if (i < 32768) {
    int k = i >> 8, m = i & 255;
    Wt1[(size_t)m * FIN + k] = (f16)W1[i];
  } else if (i < 98304) {
    int j = i - 32768;
    int k = j >> 8, m = j & 255;
    Wt2[(size_t)m * HIDDEN + k] = (f16)W2[j];
  } else if (i < 131072) {
    int j = i - 98304;
    int k = j >> 7, m = j & 127;
    Wt3[(size_t)m * HIDDEN + k] = (f16)W3[j];
  }
}

// ---------------- aggregation (f16 in, fp32 accum), 2 nodes/wave ----------------
// in is dinv-prescaled: out[i] = dinv[i]*(sum_{s in N(i)} in[s] + in[i]); FINAL adds bias, f16 out
template <int V, bool FINAL>
__global__ __launch_bounds__(256) void agg_h(const f16* __restrict__ in, f16* __restrict__ out,
                      const int* __restrict__ row_ptr, const int* __restrict__ csr_src,
                      const float* __restrict__ dinv, const float* __restrict__ bias) {
  constexpr int D = V * 32;   // row width in f16
  constexpr int U = 8;        // gathers in flight per node stream (16/wave)
  const int wid = (blockIdx.x * blockDim.x + threadIdx.x) >> 6;
  const int half = (threadIdx.x >> 5) & 1;
  const int lane = threadIdx.x & 31;
  const int node = wid * 2 + half;
  if (node >= NODES) return;
  const int c0 = lane * V;
  const f16* __restrict__ inc = in + c0;

  float acc[V];
#pragma unroll
  for (int v = 0; v < V; ++v) acc[v] = 0.f;

  const int beg = row_ptr[node], end = row_ptr[node + 1];
  int k = beg;
  if constexpr (V == 8) {
    for (; k + U <= end; k += U) {
      int s[U];
#pragma unroll
      for (int u = 0; u < U; ++u) s[u] = csr_src[k + u];
      f16x8 hv[U];
#pragma unroll
      for (int u = 0; u < U; ++u) hv[u] = *(const f16x8*)(inc + (size_t)s[u] * D);
#pragma unroll
      for (int u = 0; u < U; ++u)
#pragma unroll
        for (int v = 0; v < V; ++v) acc[v] += (float)hv[u][v];
    }
    for (; k < end; ++k) {
      f16x8 hv = *(const f16x8*)(inc + (size_t)csr_src[k] * D);
#pragma unroll
      for (int v = 0; v < V; ++v) acc[v] += (float)hv[v];
    }
    f16x8 hv = *(const f16x8*)(inc + (size_t)node * D);  // self loop
#pragma unroll
    for (int v = 0; v < V; ++v) acc[v] += (float)hv[v];
  } else {
    for (; k + U <= end; k += U) {
      int s[U];
#pragma unroll
      for (int u = 0; u < U; ++u) s[u] = csr_src[k + u];
      f16x4 hv[U];
#pragma unroll
      for (int u = 0; u < U; ++u) hv[u] = *(const f16x4*)(inc + (size_t)s[u] * D);
#pragma unroll
      for (int u = 0; u < U; ++u)
#pragma unroll
        for (int v = 0; v < V; ++v) acc[v] += (float)hv[u][v];
    }
    for (; k < end; ++k) {
      f16x4 hv = *(const f16x4*)(inc + (size_t)csr_src[k] * D);
#pragma unroll
      for (int v = 0; v < V; ++v) acc[v] += (float)hv[v];
    }
    f16x4 hv = *(const f16x4*)(inc + (size_t)node * D);  // self loop
#pragma unroll
    for (int v = 0; v < V; ++v) acc[v] += (float)hv[v];
  }

  const float di = dinv[node];
  if constexpr (FINAL) {  // V==4: h3 = di*acc + bias, f16 out
    f16x4 o;
#pragma unroll
    for (int v = 0; v < V; ++v) o[v] = (f16)(di * acc[v] + bias[c0 + v]);
    *(f16x4*)(out + (size_t)node * D + c0) = o;
  } else {
    if constexpr (V == 8) {
      f16x8 o;
#pragma unroll
      for (int v = 0; v < V; ++v) o[v] = (f16)(di * acc[v]);
      *(f16x8*)(out + (size_t)node * D + c0) = o;
    } else {
      f16x4 o;
#pragma unroll
      for (int v = 0; v < V; ++v) o[v] = (f16)(di * acc[v]);
      *(f16x4*)(out + (size_t)node * D + c0) = o;
    }
  }
}

// ---------------- wide f16 MFMA GEMM: C[N,256] = dinv*relu(A[N,K]@W[K,256]+b) ----------------
template <int K>
__global__ __launch_bounds__(256, 2) void gemm_w(const f16* __restrict__ A,
                                                 const f16* __restrict__ Wt,
                                                 const float* __restrict__ bias,
                                                 const float* __restrict__ dinv,
                                                 f16* __restrict__ C, int N) {
  constexpr int M = 256;
  __shared__ f16 As[128][40];
  __shared__ f16 Bs[256][40];

  const int tid = threadIdx.x;
  const int rowbase = blockIdx.x * 128;
  const int l = tid & 63;
  const int wv = tid >> 6;
  const int wr = (wv >> 1) * 64;   // 0 / 64
  const int wc = (wv & 1) * 128;   // 0 / 128
  const int lr = tid >> 1;
  const int lc = (tid & 1) * 16;

  f32x4 acc[4][8];
#pragma unroll
  for (int i = 0; i < 4; ++i)
#pragma unroll
    for (int j = 0; j < 8; ++j) acc[i][j] = (f32x4){0.f, 0.f, 0.f, 0.f};

  const int arow = min(rowbase + lr, N - 1);
  const f16* aptr = A + (size_t)arow * K + lc;
  const f16* bptr = Wt + (size_t)tid * K;

  for (int kb = 0; kb < K; kb += 32) {
    *(f16x8*)&As[lr][lc]     = *(const f16x8*)(aptr + kb);
    *(f16x8*)&As[lr][lc + 8] = *(const f16x8*)(aptr + kb + 8);
#pragma unroll
    for (int q = 0; q < 4; ++q)
      *(f16x8*)&Bs[tid][q * 8] = *(const f16x8*)(bptr + kb + q * 8);
    __syncthreads();

    f16x8 a[4], b[8];
#pragma unroll
    for (int f = 0; f < 4; ++f)
      a[f] = *(const f16x8*)&As[wr + f * 16 + (l & 15)][(l >> 4) * 8];
#pragma unroll
    for (int g = 0; g < 8; ++g)
      b[g] = *(const f16x8*)&Bs[wc + g * 16 + (l & 15)][(l >> 4) * 8];
#pragma unroll
    for (int fm = 0; fm < 4; ++fm)
#pragma unroll
      for (int g = 0; g < 8; ++g)
        acc[fm][g] = __builtin_amdgcn_mfma_f32_16x16x32_f16(a[fm], b[g], acc[fm][g], 0, 0, 0);
    __syncthreads();
  }

  float bv[8];
#pragma unroll
  for (int g = 0; g < 8; ++g) bv[g] = bias[wc + g * 16 + (l & 15)];

#pragma unroll
  for (int fm = 0; fm < 4; ++fm) {
#pragma unroll
    for (int r = 0; r < 4; ++r) {
      int row = rowbase + wr + fm * 16 + (l >> 4) * 4 + r;
      if (row >= N) continue;
      float dv = dinv[row];
#pragma unroll
      for (int g = 0; g < 8; ++g) {
        int col = wc + g * 16 + (l & 15);
        float v = fmaxf(acc[fm][g][r] + bv[g], 0.f);
        C[(size_t)row * M + col] = (f16)(v * dv);
      }
    }
  }
}

// ---------------- square f16 MFMA GEMM (for the 256->128 layer) ----------------
template <int K, bool RELU, bool BIAS, bool DSCALE>
__global__ __launch_bounds__(256) void gemm_h(const f16* __restrict__ A,
                                              const f16* __restrict__ Wt,
                                              const float* __restrict__ bias,
                                              const float* __restrict__ dinv,
                                              f16* __restrict__ C, int N, int M) {
  __shared__ f16 As[128][40];
  __shared__ f16 Bs[128][40];

  const int tid = threadIdx.x;
  const int rowbase = blockIdx.x * 128;
  const int colbase = blockIdx.y * 128;
  const int l = tid & 63;
  const int wr = ((tid >> 6) >> 1) * 64;
  const int wc = ((tid >> 6) & 1) * 64;
  const int lr = tid >> 1;
  const int lc = (tid & 1) * 16;

  f32x4 acc[4][4];
#pragma unroll
  for (int i = 0; i < 4; ++i)
#pragma unroll
    for (int j = 0; j < 4; ++j) acc[i][j] = (f32x4){0.f, 0.f, 0.f, 0.f};

  const int arow = min(rowbase + lr, N - 1);
  const f16* aptr = A + (size_t)arow * K + lc;
  const f16* bptr = Wt + (size_t)(colbase + lr) * K + lc;

  for (int kb = 0; kb < K; kb += 32) {
    *(f16x8*)&As[lr][lc]     = *(const f16x8*)(aptr + kb);
    *(f16x8*)&As[lr][lc + 8] = *(const f16x8*)(aptr + kb + 8);
    *(f16x8*)&Bs[lr][lc]     = *(const f16x8*)(bptr + kb);
    *(f16x8*)&Bs[lr][lc + 8] = *(const f16x8*)(bptr + kb + 8);
    __syncthreads();

    f16x8 a[4], b[4];
#pragma unroll
    for (int f = 0; f < 4; ++f) {
      a[f] = *(const f16x8*)&As[wr + f * 16 + (l & 15)][(l >> 4) * 8];
      b[f] = *(const f16x8*)&Bs[wc + f * 16 + (l & 15)][(l >> 4) * 8];
    }
#pragma unroll
    for (int fm = 0; fm < 4; ++fm)
#pragma unroll
      for (int fn = 0; fn < 4; ++fn)
        acc[fm][fn] = __builtin_amdgcn_mfma_f32_16x16x32_f16(a[fm], b[fn], acc[fm][fn], 0, 0, 0);
    __syncthreads();
  }

  float bv[4];
#pragma unroll
  for (int fn = 0; fn < 4; ++fn)
    bv[fn] = BIAS ? bias[colbase + wc + fn * 16 + (l & 15)] : 0.f;

#pragma unroll
  for (int fm = 0; fm < 4; ++fm) {
#pragma unroll
    for (int r = 0; r < 4; ++r) {
      int row = rowbase + wr + fm * 16 + (l >> 4) * 4 + r;
      if (row >= N) continue;
      float dv = DSCALE ? dinv[row] : 1.f;
#pragma unroll
      for (int fn = 0; fn < 4; ++fn) {
        int col = colbase + wc + fn * 16 + (l & 15);
        float v = acc[fm][fn][r] + bv[fn];
        if (RELU) v = fmaxf(v, 0.f);
        C[(size_t)row * M + col] = (f16)(v * dv);
      }
    }
  }
}

// ---------------- fp32 GEMM for the tiny head (N=2048) ----------------
template <int K, bool RELU, bool HAS_BIAS>
__global__ __launch_bounds__(256) void gemm_k(const float* __restrict__ A,
                                              const float* __restrict__ W,
                                              const float* __restrict__ bias,
                                              float* __restrict__ C, int N, int M) {
  constexpr int KB = 16;
  __shared__ float As[KB][128];
  __shared__ float Ws[KB][128];

  const int tid = threadIdx.x;
  const int rowbase = blockIdx.x * 128;
  const int colbase = blockIdx.y * 128;
  const int tr = tid >> 4;
  const int tc = tid & 15;
  const int ar = tid >> 1;
  const int ac4_0 = (tid & 1) * 2;
  const int wk = tid >> 4;
  const int wc4_0 = (tid & 15) * 2;

  float acc[8][8];
#pragma unroll
  for (int i = 0; i < 8; ++i)
#pragma unroll
    for (int j = 0; j < 8; ++j) acc[i][j] = 0.f;

  for (int kb = 0; kb < K; kb += KB) {
#pragma unroll
    for (int q = 0; q < 2; ++q) {
      int c4 = ac4_0 + q;
      int grow = rowbase + ar;
      float4 v = make_float4(0.f, 0.f, 0.f, 0.f);
      if (grow < N) v = *(const float4*)(A + (size_t)grow * K + kb + c4 * 4);
      As[c4 * 4 + 0][ar] = v.x;
      As[c4 * 4 + 1][ar] = v.y;
      As[c4 * 4 + 2][ar] = v.z;
      As[c4 * 4 + 3][ar] = v.w;
    }
#pragma unroll
    for (int q = 0; q < 2; ++q) {
      int c4 = wc4_0 + q;
      float4 v = *(const float4*)(W + (size_t)(kb + wk) * M + colbase + c4 * 4);
      *(float4*)&Ws[wk][c4 * 4] = v;
    }
    __syncthreads();

#pragma unroll
    for (int kk = 0; kk < KB; ++kk) {
      float4 a0 = *(const float4*)&As[kk][tr * 4];
      float4 a1 = *(const float4*)&As[kk][tr * 4 + 64];
      float4 w0 = *(const float4*)&Ws[kk][tc * 4];
      float4 w1 = *(const float4*)&Ws[kk][tc * 4 + 64];
      float a[8] = {a0.x, a0.y, a0.z, a0.w, a1.x, a1.y, a1.z, a1.w};
      float w[8] = {w0.x, w0.y, w0.z, w0.w, w1.x, w1.y, w1.z, w1.w};
#pragma unroll
      for (int i = 0; i < 8; ++i)
#pragma unroll
        for (int j = 0; j < 8; ++j) acc[i][j] = fmaf(a[i], w[j], acc[i][j]);
    }
    __syncthreads();
  }

#pragma unroll
  for (int i = 0; i < 8; ++i) {
    int r = rowbase + ((i < 4) ? (tr * 4 + i) : (64 + tr * 4 + (i - 4)));
    if (r >= N) continue;
#pragma unroll
    for (int jh = 0; jh < 2; ++jh) {
      int c = colbase + tc * 4 + jh * 64;
      float4 o;
      o.x = acc[i][jh * 4 + 0];
      o.y = acc[i][jh * 4 + 1];
      o.z = acc[i][jh * 4 + 2];
      o.w = acc[i][jh * 4 + 3];
      if (HAS_BIAS) {
        o.x += bias[c]; o.y += bias[c + 1]; o.z += bias[c + 2]; o.w += bias[c + 3];
      }
      if (RELU) {
        o.x = fmaxf(o.x, 0.f); o.y = fmaxf(o.y, 0.f);
        o.z = fmaxf(o.z, 0.f); o.w = fmaxf(o.w, 0.f);
      }
      *(float4*)(C + (size_t)r * M + c) = o;
    }
  }
}

// ---------------- mean pooling per graph (batch sorted), f16 input ----------------
__global__ void pool_k(const f16* __restrict__ h, const int* __restrict__ batch,
                       float* __restrict__ pooled) {
  int g = blockIdx.x;
  int j = threadIdx.x;  // 128 threads = EMBD
  int lo = 0, hi = NODES;
  while (lo < hi) { int mid = (lo + hi) >> 1; if (batch[mid] < g) lo = mid + 1; else hi = mid; }
  int start = lo;
  int lo2 = start, hi2 = NODES;
  while (lo2 < hi2) { int mid = (lo2 + hi2) >> 1; if (batch[mid] < g + 1) lo2 = mid + 1; else hi2 = mid; }
  int end = lo2;
  float s = 0.f;
  for (int r = start; r < end; ++r) s += (float)h[(size_t)r * EMBD + j];
  float c = (float)(end - start);
  pooled[g * EMBD + j] = s / fmaxf(c, 1.f);
}

// ---------------- head: logits = z2 @ Wc3[128,2] + bc3 ----------------
__global__ void head_k(const float* __restrict__ z2, const float* __restrict__ Wc3,
                       const float* __restrict__ bc3, float* __restrict__ out) {
  int wv = (blockIdx.x * blockDim.x + threadIdx.x) >> 6;
  int lane = threadIdx.x & 63;
  if (wv >= GRAPHS) return;
  float2 z = *(const float2*)(z2 + (size_t)wv * 128 + lane * 2);
  int j0 = lane * 2;
  float a0 = z.x * Wc3[j0 * 2 + 0] + z.y * Wc3[(j0 + 1) * 2 + 0];
  float a1 = z.x * Wc3[j0 * 2 + 1] + z.y * Wc3[(j0 + 1) * 2 + 1];
  for (int off = 32; off; off >>= 1) {
    a0 += __shfl_down(a0, off);
    a1 += __shfl_down(a1, off);
  }
  if (lane == 0) {
    out[wv * 2 + 0] = a0 + bc3[0];
    out[wv * 2 + 1] = a1 + bc3[1];
  }
}

extern "C" void kernel_launch(void* const* d_in, const int* in_sizes, int n_in,
                              void* d_out, int out_size, void* d_ws, size_t ws_size,
                              hipStream_t stream) {
  const float* x    = (const float*)d_in[0];
  const int*   ei   = (const int*)d_in[1];
  const int*   batch= (const int*)d_in[2];
  const float* W1 = (const float*)d_in[3];  const float* b1 = (const float*)d_in[4];
  const float* W2 = (const float*)d_in[5];  const float* b2 = (const float*)d_in[6];
  const float* W3 = (const float*)d_in[7];  const float* b3 = (const float*)d_in[8];
  const float* Wc1= (const float*)d_in[9];  const float* bc1= (const float*)d_in[10];
  const float* Wc2= (const float*)d_in[11]; const float* bc2= (const float*)d_in[12];
  const float* Wc3= (const float*)d_in[13]; const float* bc3= (const float*)d_in[14];
  float* out = (float*)d_out;

  char* ws = (char*)d_ws;
  size_t off = 0;
  auto alloc = [&](size_t bytes) -> void* {
    void* p = ws + off;
    off = (off + bytes + 255) & ~(size_t)255;
    return p;
  };
  f16*   F0      = (f16*)alloc((size_t)NODES * 256 * 2);
  f16*   F1      = (f16*)alloc((size_t)NODES * 256 * 2);
  f16*   hbuf    = (f16*)alloc((size_t)NODES * 128 * 2);
  int*   csr_src = (int*)alloc((size_t)EDGES * 4);
  u32*   staging = (u32*)alloc((size_t)NB * CAP * 4);
  int*   row_ptr = (int*)alloc((size_t)(NODES + 1) * 4);
  float* dinv    = (float*)alloc((size_t)NODES * 4);
  int*   gcur    = (int*)alloc(NB * 4);
  int*   bbase   = (int*)alloc(NB * 4);
  f16*   Wt1     = (f16*)alloc((size_t)FIN * HIDDEN * 2);
  f16*   Wt2     = (f16*)alloc((size_t)HIDDEN * HIDDEN * 2);
  f16*   Wt3     = (f16*)alloc((size_t)HIDDEN * EMBD * 2);
  // fp32 overlays in F1 (dead after the final agg consumed it)
  float* pooled = (float*)F1;
  float* z1     = pooled + (size_t)GRAPHS * EMBD;
  float* z2     = z1 + (size_t)GRAPHS * HIDDEN;

  const int* srcA = ei;
  const int* dstA = ei + EDGES;

  // ---- CSR build: two-phase LDS bin-sort (+fused prescale -> F0 128-wide) ----
  hipMemsetAsync(gcur, 0, NB * 4, stream);
  binA_k<<<(EDGES + TILE - 1) / TILE, 256, 0, stream>>>(srcA, dstA, staging, gcur);
  bscan_k<<<1, NB, 0, stream>>>(gcur, bbase);
  binB_k<<<NB, 512, 0, stream>>>(staging, gcur, bbase, row_ptr, dinv, csr_src, x, F0);

  convw3_k<<<(131072 + 255) / 256, 256, 0, stream>>>(W1, W2, W3, Wt1, Wt2, Wt3);

  const int aggBlocks = ((NODES + 1) / 2 * 64 + 255) / 256;  // 12500
  const int gemmRows = (NODES + 127) / 128;                  // 782

  // L1: AX = dinv*(sum xs) [128 f16] F0->F1; H1s = dinv*relu(AX@W1+b1) [256 f16] F1->F0
  agg_h<4, false><<<aggBlocks, 256, 0, stream>>>(F0, F1, row_ptr, csr_src, dinv, nullptr);
  gemm_w<FIN><<<gemmRows, 256, 0, stream>>>(F1, Wt1, b1, dinv, F0, NODES);
  // L2: AH1 = dinv*(sum H1s) [256 f16] F0->F1; H2s = dinv*relu(AH1@W2+b2) F1->F0
  agg_h<8, false><<<aggBlocks, 256, 0, stream>>>(F0, F1, row_ptr, csr_src, dinv, nullptr);
  gemm_w<HIDDEN><<<gemmRows, 256, 0, stream>>>(F1, Wt2, b2, dinv, F0, NODES);
  // L3: G3s = H2s@W3 [128 f16] F0->F1; h3 = dinv*(sum G3s)+b3 [128 f16] F1->hbuf
  gemm_h<HIDDEN, false, false, false><<<dim3(gemmRows, 1), 256, 0, stream>>>(F0, Wt3, nullptr, nullptr, F1, NODES, EMBD);
  agg_h<4, true><<<aggBlocks, 256, 0, stream>>>(F1, hbuf, row_ptr, csr_src, dinv, b3);

  // pooling + MLP head (fp32)
  pool_k<<<GRAPHS, 128, 0, stream>>>(hbuf, batch, pooled);
  gemm_k<EMBD, true, true><<<dim3((GRAPHS + 127) / 128, 2), 256, 0, stream>>>(pooled, Wc1, bc1, z1, GRAPHS, HIDDEN);
  gemm_k<HIDDEN, true, true><<<dim3((GRAPHS + 127) / 128, 1), 256, 0, stream>>>(z1, Wc2, bc2, z2, GRAPHS, EMBD);
  head_k<<<GRAPHS / 4, 256, 0, stream>>>(z2, Wc3, bc3, out);
}